// Round 16
// baseline (34.733 us; speedup 1.0000x reference)
//
#include <hip/hip_runtime.h>
#include <hip/hip_fp16.h>
#include <math.h>

#define NFIELDS 50
#define EMBD 64
#define NPAIRS 1225
#define NTILEPAD 40            // 4 waves x 10 tiles per element
#define NPAD (NTILEPAD * 32)   // 1280
#define NSEQ 2                 // elements processed sequentially per block
#define NWAVES 4
#define NITER 10               // tiles per wave per element
#define NTHREADS 256
#define NFPAD 51
#define CHSTR (NFPAD * 8)      // u16 units per chunk slab = 408

typedef _Float16 f16x8 __attribute__((ext_vector_type(8)));
typedef _Float16 f16x2 __attribute__((ext_vector_type(2)));
typedef __fp16   fp16x2 __attribute__((ext_vector_type(2)));
typedef float f32x16 __attribute__((ext_vector_type(16)));

union F16x8U { f16x8 v; f16x2 h2[4]; unsigned int u[4]; uint4 q; };
union U32F { unsigned int u; f16x2 h; fp16x2 g; };

__device__ __forceinline__ f16x2 pkrtz(float a, float b) {
    U32F t; t.g = __builtin_amdgcn_cvt_pkrtz(a, b);
    return t.h;
}

__device__ __forceinline__ f16x2 pkmax0(f16x2 a) {
#if __has_builtin(__builtin_elementwise_max)
    f16x2 z; z[0] = (_Float16)0; z[1] = (_Float16)0;
    return __builtin_elementwise_max(a, z);
#else
    f16x2 r;
    r[0] = a[0] > (_Float16)0 ? a[0] : (_Float16)0;
    r[1] = a[1] > (_Float16)0 ? a[1] : (_Float16)0;
    return r;
#endif
}

// 1024 blocks x 256 threads (4 blocks/CU => 16 waves/CU) with R15's
// sequential-element + pipelined-gather structure at NSEQ=2.
// Combines the TLP lever (R13) with the amortization/prefetch lever (R15).
__launch_bounds__(NTHREADS, 4)
__global__ void afm_kernel(const int* __restrict__ features,
                           const float* __restrict__ emb_table,
                           const float* __restrict__ coeff_table,
                           const float* __restrict__ bias,
                           const float* __restrict__ att_w,
                           const float* __restrict__ att_b,
                           const float* __restrict__ pvec,
                           const float* __restrict__ wvec,
                           float* __restrict__ out)
{
    __shared__ __align__(16) unsigned short emb3[2][8][NFPAD][8]; // dbuf chunk-major
    __shared__ unsigned short pair_s[NPAD];     // (i<<8)|j
    __shared__ int   feat_s[NSEQ][NFIELDS];
    __shared__ float red_s[2][NWAVES], red_st[2][NWAVES];  // dbuf reduce slots
    __shared__ float csum_s[NSEQ];

    const int b0   = blockIdx.x * NSEQ;
    const int tid  = threadIdx.x;
    const int lane = tid & 63;
    const int wid  = tid >> 6;
    const int col  = lane & 31;   // MFMA output col = pair within tile
    const int h    = lane >> 5;   // k-half
    const int h4   = h * 4;

    // ---- prologue A: wave w (<NSEQ) loads features+coeff of element w ----
    if (wid < NSEQ) {
        float cacc = 0.f;
        if (lane < NFIELDS) {
            const int f = features[(b0 + wid) * NFIELDS + lane];
            feat_s[wid][lane] = f;
            cacc = coeff_table[f];
        } else if (lane == NFIELDS) {
            cacc = bias[0];
        }
        #pragma unroll
        for (int m = 1; m < 64; m <<= 1) cacc += __shfl_xor(cacc, m, 64);
        if (lane == 0) csum_s[wid] = cacc;
    }

    // ---- prologue B: pair table (closed-form triangular inverse) ----
    #pragma unroll
    for (int k = 0; k < NPAD / NTHREADS; ++k) {
        const int q = tid + k * NTHREADS;
        int i = 0, j = 1;
        if (q < NPAIRS) {
            const float s = sqrtf((float)(9801 - 8 * q));   // exact: 99-2i odd sq
            i = (int)((99.0f - s) * 0.5f);
            const int off = i * NFIELDS - ((i * (i + 1)) >> 1);
            j = i + 1 + (q - off);
        }
        pair_s[q] = (unsigned short)((i << 8) | j);
    }

    // ---- prologue C: per-lane register weights (element-independent) ----
    f16x8 afragW[4];
    f16x2 w2[16];
    #pragma unroll
    for (int c = 0; c < 4; ++c) {
        const int d0 = c * 16 + h * 8;
        const float4 wa0 = *reinterpret_cast<const float4*>(&att_w[col * EMBD + d0]);
        const float4 wa1 = *reinterpret_cast<const float4*>(&att_w[col * EMBD + d0 + 4]);
        F16x8U bf;
        bf.v[0] = (_Float16)wa0.x; bf.v[1] = (_Float16)wa0.y;
        bf.v[2] = (_Float16)wa0.z; bf.v[3] = (_Float16)wa0.w;
        bf.v[4] = (_Float16)wa1.x; bf.v[5] = (_Float16)wa1.y;
        bf.v[6] = (_Float16)wa1.z; bf.v[7] = (_Float16)wa1.w;
        afragW[c] = bf.v;
        const float4 wv0 = *reinterpret_cast<const float4*>(&wvec[d0]);
        const float4 wv1 = *reinterpret_cast<const float4*>(&wvec[d0 + 4]);
        f16x2 t0; t0[0] = (_Float16)wv0.x; t0[1] = (_Float16)wv0.y; w2[c * 4 + 0] = t0;
        f16x2 t1; t1[0] = (_Float16)wv0.z; t1[1] = (_Float16)wv0.w; w2[c * 4 + 1] = t1;
        f16x2 t2; t2[0] = (_Float16)wv1.x; t2[1] = (_Float16)wv1.y; w2[c * 4 + 2] = t2;
        f16x2 t3; t3[0] = (_Float16)wv1.z; t3[1] = (_Float16)wv1.w; w2[c * 4 + 3] = t3;
    }
    // row(reg) = (reg&3) + 8*(reg>>2) + 4*h
    float attb_r[16];
    f16x2 p16[8];
    #pragma unroll
    for (int q = 0; q < 4; ++q) {
        const float4 ab = *reinterpret_cast<const float4*>(&att_b[8 * q + 4 * h]);
        attb_r[4 * q + 0] = ab.x; attb_r[4 * q + 1] = ab.y;
        attb_r[4 * q + 2] = ab.z; attb_r[4 * q + 3] = ab.w;
        const float4 pp = *reinterpret_cast<const float4*>(&pvec[8 * q + 4 * h]);
        f16x2 pa; pa[0] = (_Float16)pp.x; pa[1] = (_Float16)pp.y; p16[2 * q]     = pa;
        f16x2 pb; pb[0] = (_Float16)pp.z; pb[1] = (_Float16)pp.w; p16[2 * q + 1] = pb;
    }
    __syncthreads();   // feat_s / pair_s / csum_s ready

    // ---- gather staging: issue-early (regs), write-late (LDS) ----
    float4 greg[4];

#define GISSUE(ee)                                                          \
    {                                                                       \
        _Pragma("unroll")                                                   \
        for (int k = 0; k < 4; ++k) {                                       \
            const int idx = tid + k * NTHREADS;                             \
            if (idx < NFIELDS * 16) {                                       \
                const int f  = idx >> 4;                                    \
                const int d0 = (idx & 15) * 4;                              \
                greg[k] = *reinterpret_cast<const float4*>(                 \
                    &emb_table[(size_t)feat_s[ee][f] * EMBD + d0]);         \
            }                                                               \
        }                                                                   \
    }

#define GWRITE(buf)                                                         \
    {                                                                       \
        _Pragma("unroll")                                                   \
        for (int k = 0; k < 4; ++k) {                                       \
            const int idx = tid + k * NTHREADS;                             \
            if (idx < NFIELDS * 16) {                                       \
                const int f  = idx >> 4;                                    \
                const int d0 = (idx & 15) * 4;                              \
                const int c  = d0 >> 4;                                     \
                const int hh = (d0 >> 3) & 1;                               \
                const int e0 = d0 & 7;                                      \
                U32F t0, t1;                                                \
                t0.h[0] = (_Float16)greg[k].x; t0.h[1] = (_Float16)greg[k].y; \
                t1.h[0] = (_Float16)greg[k].z; t1.h[1] = (_Float16)greg[k].w; \
                uint2 pk; pk.x = t0.u; pk.y = t1.u;                         \
                *reinterpret_cast<uint2*>(&emb3[buf][hh * 4 + c][f][e0]) = pk; \
            }                                                               \
        }                                                                   \
    }

    // prime the pipeline: element 0 -> buffer 0
    GISSUE(0);
    GWRITE(0);
    __syncthreads();

    #pragma unroll 1
    for (int e = 0; e < NSEQ; ++e) {
        // issue next element's gather NOW (lands under this element's compute)
        if (e + 1 < NSEQ) GISSUE(e + 1);

        const unsigned short* const ebase =
            &emb3[e & 1][0][0][0] + h4 * CHSTR;
        float s_run = 0.f, st_run = 0.f;

        #pragma unroll 2
        for (int tt = 0; tt < NITER; ++tt) {
            const int tile = wid + tt * NWAVES;
            const int q    = tile * 32 + col;
            const unsigned int ij = pair_s[q];
            const int fi = ij >> 8;
            const int fj = ij & 255;

            const unsigned short* pi = ebase + fi * 8;
            const unsigned short* pj = ebase + fj * 8;

            f32x16 acc;
            #pragma unroll
            for (int reg = 0; reg < 16; ++reg) acc[reg] = attb_r[reg];

            f16x2 th2; th2[0] = (_Float16)0; th2[1] = (_Float16)0;
            #pragma unroll
            for (int c = 0; c < 4; ++c) {
                F16x8U ai, aj;
                ai.q = *reinterpret_cast<const uint4*>(pi + c * CHSTR);
                aj.q = *reinterpret_cast<const uint4*>(pj + c * CHSTR);
                const f16x2 x0 = ai.h2[0] * aj.h2[0];   // v_pk_mul_f16
                const f16x2 x1 = ai.h2[1] * aj.h2[1];
                const f16x2 x2 = ai.h2[2] * aj.h2[2];
                const f16x2 x3 = ai.h2[3] * aj.h2[3];
                th2 = x0 * w2[c * 4 + 0] + th2;          // v_pk_fma_f16
                th2 = x1 * w2[c * 4 + 1] + th2;
                th2 = x2 * w2[c * 4 + 2] + th2;
                th2 = x3 * w2[c * 4 + 3] + th2;
                F16x8U bf;
                bf.h2[0] = x0; bf.h2[1] = x1; bf.h2[2] = x2; bf.h2[3] = x3;
                acc = __builtin_amdgcn_mfma_f32_32x32x16_f16(afragW[c], bf.v, acc, 0, 0, 0);
            }

            // epilogue: packed-f16 relu + dot with p over 16 in-register rows
            f16x2 sp2; sp2[0] = (_Float16)0; sp2[1] = (_Float16)0;
            #pragma unroll
            for (int qq = 0; qq < 8; ++qq) {
                const f16x2 av = pkmax0(pkrtz(acc[2 * qq], acc[2 * qq + 1]));
                sp2 = av * p16[qq] + sp2;                // v_pk_fma_f16
            }
            const float sp     = (float)sp2[0] + (float)sp2[1];
            const float t_half = (float)th2[0] + (float)th2[1];

            // one cross-half exchange for (sp, t_half) packed as 2xf16
            U32F pkd, oth;
            pkd.h = pkrtz(sp, t_half);
            oth.u = (unsigned int)__shfl_xor((int)pkd.u, 32, 64);
            const float sc = sp + (float)oth.h[0];
            const float tf = t_half + (float)oth.h[1];

            // no-max accumulate (scores O(0.03) << 88; h dups cancel in ST/S)
            const float ex = (q < NPAIRS) ? __expf(sc) : 0.f;
            s_run  += ex;
            st_run += ex * tf;
        }

        // wave butterfly, stash into this element's reduce slots
        #pragma unroll
        for (int m = 1; m < 64; m <<= 1) {
            s_run  += __shfl_xor(s_run, m, 64);
            st_run += __shfl_xor(st_run, m, 64);
        }
        if (lane == 0) { red_s[e & 1][wid] = s_run; red_st[e & 1][wid] = st_run; }

        // write next element's gather into the other LDS buffer
        if (e + 1 < NSEQ) GWRITE((e + 1) & 1);
        __syncthreads();

        if (tid == 0) {
            const float S  = red_s[e & 1][0] + red_s[e & 1][1]
                           + red_s[e & 1][2] + red_s[e & 1][3];
            const float ST = red_st[e & 1][0] + red_st[e & 1][1]
                           + red_st[e & 1][2] + red_st[e & 1][3];
            out[b0 + e] = ST / S + csum_s[e];
        }
    }

#undef GISSUE
#undef GWRITE
}

extern "C" void kernel_launch(void* const* d_in, const int* in_sizes, int n_in,
                              void* d_out, int out_size, void* d_ws, size_t ws_size,
                              hipStream_t stream) {
    const int*   features    = (const int*)d_in[0];
    const float* emb_table   = (const float*)d_in[1];
    const float* coeff_table = (const float*)d_in[2];
    const float* bias        = (const float*)d_in[3];
    const float* att_w       = (const float*)d_in[4];
    const float* att_b       = (const float*)d_in[5];
    const float* pvec        = (const float*)d_in[6];
    const float* wvec        = (const float*)d_in[7];
    float* out = (float*)d_out;

    const int batch = in_sizes[0] / NFIELDS;   // 2048
    afm_kernel<<<batch / NSEQ, NTHREADS, 0, stream>>>(
        features, emb_table, coeff_table, bias, att_w, att_b, pvec, wvec, out);
}

// Round 17
// 30.042 us; speedup vs baseline: 1.1561x; 1.1561x over previous
//
#include <hip/hip_runtime.h>
#include <hip/hip_fp16.h>
#include <math.h>

#define NFIELDS 50
#define EMBD 64
#define NPAIRS 1225
#define NTILEPAD 40            // 4 waves x 10 tiles per element
#define NPAD (NTILEPAD * 32)   // 1280
#define NGRP 2                 // independent 4-wave groups per block
#define NSEQ 4                 // elements per group, sequential
#define NWAVES 4               // waves per group
#define NITER 10               // tiles per wave per element
#define NTHREADS 512
#define NFPAD 51
#define CHSTR (NFPAD * 8)      // u16 units per chunk slab = 408

typedef _Float16 f16x8 __attribute__((ext_vector_type(8)));
typedef _Float16 f16x2 __attribute__((ext_vector_type(2)));
typedef __fp16   fp16x2 __attribute__((ext_vector_type(2)));
typedef float f32x16 __attribute__((ext_vector_type(16)));

union F16x8U { f16x8 v; f16x2 h2[4]; unsigned int u[4]; uint4 q; };
union U32F { unsigned int u; f16x2 h; fp16x2 g; };

__device__ __forceinline__ f16x2 pkrtz(float a, float b) {
    U32F t; t.g = __builtin_amdgcn_cvt_pkrtz(a, b);
    return t.h;
}

__device__ __forceinline__ f16x2 pkmax0(f16x2 a) {
#if __has_builtin(__builtin_elementwise_max)
    f16x2 z; z[0] = (_Float16)0; z[1] = (_Float16)0;
    return __builtin_elementwise_max(a, z);
#else
    f16x2 r;
    r[0] = a[0] > (_Float16)0 ? a[0] : (_Float16)0;
    r[1] = a[1] > (_Float16)0 ? a[1] : (_Float16)0;
    return r;
#endif
}

// 256 blocks x 512 threads = 1 block/CU, single residency round.
// Each block: 2 independent 4-wave groups; each group runs a NSEQ=4
// sequential pipeline (R15 structure) over its own 4 batch elements.
// Per-CU concurrency = R15 (8 waves, 2 pipelines); prologue amortized 8x;
// launch ramp halved (256 vs 512 blocks, one round).
__launch_bounds__(NTHREADS, 2)
__global__ void afm_kernel(const int* __restrict__ features,
                           const float* __restrict__ emb_table,
                           const float* __restrict__ coeff_table,
                           const float* __restrict__ bias,
                           const float* __restrict__ att_w,
                           const float* __restrict__ att_b,
                           const float* __restrict__ pvec,
                           const float* __restrict__ wvec,
                           float* __restrict__ out)
{
    __shared__ __align__(16) unsigned short emb3[NGRP][2][8][NFPAD][8]; // dbuf
    __shared__ unsigned short pair_s[NPAD];     // (i<<8)|j
    __shared__ int   feat_s[NGRP * NSEQ][NFIELDS];
    __shared__ float red_s[NGRP][2][NWAVES], red_st[NGRP][2][NWAVES];
    __shared__ float csum_s[NGRP * NSEQ];

    const int b0   = blockIdx.x * (NGRP * NSEQ);
    const int tid  = threadIdx.x;
    const int lane = tid & 63;
    const int wid  = tid >> 6;    // 0..7
    const int grp  = wid >> 2;    // 0..1
    const int wg   = wid & 3;     // wave within group
    const int col  = lane & 31;   // MFMA output col = pair within tile
    const int h    = lane >> 5;   // k-half
    const int h4   = h * 4;
    const int tg   = tid & 255;   // thread id within group

    // ---- prologue A: wave w loads features+coeff of block-element w ----
    {
        float cacc = 0.f;
        if (lane < NFIELDS) {
            const int f = features[(b0 + wid) * NFIELDS + lane];
            feat_s[wid][lane] = f;
            cacc = coeff_table[f];
        } else if (lane == NFIELDS) {
            cacc = bias[0];
        }
        #pragma unroll
        for (int m = 1; m < 64; m <<= 1) cacc += __shfl_xor(cacc, m, 64);
        if (lane == 0) csum_s[wid] = cacc;
    }

    // ---- prologue B: pair table (closed-form triangular inverse) ----
    #pragma unroll
    for (int k = 0; k < 3; ++k) {
        const int q = tid + k * NTHREADS;
        if (q < NPAD) {
            int i = 0, j = 1;
            if (q < NPAIRS) {
                const float s = sqrtf((float)(9801 - 8 * q)); // exact: odd square
                i = (int)((99.0f - s) * 0.5f);
                const int off = i * NFIELDS - ((i * (i + 1)) >> 1);
                j = i + 1 + (q - off);
            }
            pair_s[q] = (unsigned short)((i << 8) | j);
        }
    }

    // ---- prologue C: per-lane register weights (element-independent) ----
    f16x8 afragW[4];
    f16x2 w2[16];
    #pragma unroll
    for (int c = 0; c < 4; ++c) {
        const int d0 = c * 16 + h * 8;
        const float4 wa0 = *reinterpret_cast<const float4*>(&att_w[col * EMBD + d0]);
        const float4 wa1 = *reinterpret_cast<const float4*>(&att_w[col * EMBD + d0 + 4]);
        F16x8U bf;
        bf.v[0] = (_Float16)wa0.x; bf.v[1] = (_Float16)wa0.y;
        bf.v[2] = (_Float16)wa0.z; bf.v[3] = (_Float16)wa0.w;
        bf.v[4] = (_Float16)wa1.x; bf.v[5] = (_Float16)wa1.y;
        bf.v[6] = (_Float16)wa1.z; bf.v[7] = (_Float16)wa1.w;
        afragW[c] = bf.v;
        const float4 wv0 = *reinterpret_cast<const float4*>(&wvec[d0]);
        const float4 wv1 = *reinterpret_cast<const float4*>(&wvec[d0 + 4]);
        f16x2 t0; t0[0] = (_Float16)wv0.x; t0[1] = (_Float16)wv0.y; w2[c * 4 + 0] = t0;
        f16x2 t1; t1[0] = (_Float16)wv0.z; t1[1] = (_Float16)wv0.w; w2[c * 4 + 1] = t1;
        f16x2 t2; t2[0] = (_Float16)wv1.x; t2[1] = (_Float16)wv1.y; w2[c * 4 + 2] = t2;
        f16x2 t3; t3[0] = (_Float16)wv1.z; t3[1] = (_Float16)wv1.w; w2[c * 4 + 3] = t3;
    }
    // row(reg) = (reg&3) + 8*(reg>>2) + 4*h
    float attb_r[16];
    f16x2 p16[8];
    #pragma unroll
    for (int q = 0; q < 4; ++q) {
        const float4 ab = *reinterpret_cast<const float4*>(&att_b[8 * q + 4 * h]);
        attb_r[4 * q + 0] = ab.x; attb_r[4 * q + 1] = ab.y;
        attb_r[4 * q + 2] = ab.z; attb_r[4 * q + 3] = ab.w;
        const float4 pp = *reinterpret_cast<const float4*>(&pvec[8 * q + 4 * h]);
        f16x2 pa; pa[0] = (_Float16)pp.x; pa[1] = (_Float16)pp.y; p16[2 * q]     = pa;
        f16x2 pb; pb[0] = (_Float16)pp.z; pb[1] = (_Float16)pp.w; p16[2 * q + 1] = pb;
    }
    __syncthreads();   // feat_s / pair_s / csum_s ready

    // ---- gather staging (per group): issue-early (regs), write-late (LDS) ----
    float4 greg[4];

#define GISSUE(ei)                                                          \
    {                                                                       \
        _Pragma("unroll")                                                   \
        for (int k = 0; k < 4; ++k) {                                       \
            const int idx = tg + k * 256;                                   \
            if (idx < NFIELDS * 16) {                                       \
                const int f  = idx >> 4;                                    \
                const int d0 = (idx & 15) * 4;                              \
                greg[k] = *reinterpret_cast<const float4*>(                 \
                    &emb_table[(size_t)feat_s[ei][f] * EMBD + d0]);         \
            }                                                               \
        }                                                                   \
    }

#define GWRITE(buf)                                                         \
    {                                                                       \
        _Pragma("unroll")                                                   \
        for (int k = 0; k < 4; ++k) {                                       \
            const int idx = tg + k * 256;                                   \
            if (idx < NFIELDS * 16) {                                       \
                const int f  = idx >> 4;                                    \
                const int d0 = (idx & 15) * 4;                              \
                const int c  = d0 >> 4;                                     \
                const int hh = (d0 >> 3) & 1;                               \
                const int e0 = d0 & 7;                                      \
                U32F t0, t1;                                                \
                t0.h[0] = (_Float16)greg[k].x; t0.h[1] = (_Float16)greg[k].y; \
                t1.h[0] = (_Float16)greg[k].z; t1.h[1] = (_Float16)greg[k].w; \
                uint2 pk; pk.x = t0.u; pk.y = t1.u;                         \
                *reinterpret_cast<uint2*>(&emb3[grp][buf][hh * 4 + c][f][e0]) = pk; \
            }                                                               \
        }                                                                   \
    }

    // prime the pipeline: group's element 0 -> buffer 0
    GISSUE(grp * NSEQ + 0);
    GWRITE(0);
    __syncthreads();

    #pragma unroll 1
    for (int e = 0; e < NSEQ; ++e) {
        const int ei = grp * NSEQ + e;
        // issue next element's gather NOW (lands under this element's compute)
        if (e + 1 < NSEQ) GISSUE(ei + 1);

        const unsigned short* const ebase =
            &emb3[grp][e & 1][0][0][0] + h4 * CHSTR;
        float s_run = 0.f, st_run = 0.f;

        #pragma unroll 2
        for (int tt = 0; tt < NITER; ++tt) {
            const int tile = wg + tt * NWAVES;
            const int q    = tile * 32 + col;
            const unsigned int ij = pair_s[q];
            const int fi = ij >> 8;
            const int fj = ij & 255;

            const unsigned short* pi = ebase + fi * 8;
            const unsigned short* pj = ebase + fj * 8;

            f32x16 acc;
            #pragma unroll
            for (int reg = 0; reg < 16; ++reg) acc[reg] = attb_r[reg];

            f16x2 th2; th2[0] = (_Float16)0; th2[1] = (_Float16)0;
            #pragma unroll
            for (int c = 0; c < 4; ++c) {
                F16x8U ai, aj;
                ai.q = *reinterpret_cast<const uint4*>(pi + c * CHSTR);
                aj.q = *reinterpret_cast<const uint4*>(pj + c * CHSTR);
                const f16x2 x0 = ai.h2[0] * aj.h2[0];   // v_pk_mul_f16
                const f16x2 x1 = ai.h2[1] * aj.h2[1];
                const f16x2 x2 = ai.h2[2] * aj.h2[2];
                const f16x2 x3 = ai.h2[3] * aj.h2[3];
                th2 = x0 * w2[c * 4 + 0] + th2;          // v_pk_fma_f16
                th2 = x1 * w2[c * 4 + 1] + th2;
                th2 = x2 * w2[c * 4 + 2] + th2;
                th2 = x3 * w2[c * 4 + 3] + th2;
                F16x8U bf;
                bf.h2[0] = x0; bf.h2[1] = x1; bf.h2[2] = x2; bf.h2[3] = x3;
                acc = __builtin_amdgcn_mfma_f32_32x32x16_f16(afragW[c], bf.v, acc, 0, 0, 0);
            }

            // epilogue: packed-f16 relu + dot with p over 16 in-register rows
            f16x2 sp2; sp2[0] = (_Float16)0; sp2[1] = (_Float16)0;
            #pragma unroll
            for (int qq = 0; qq < 8; ++qq) {
                const f16x2 av = pkmax0(pkrtz(acc[2 * qq], acc[2 * qq + 1]));
                sp2 = av * p16[qq] + sp2;                // v_pk_fma_f16
            }
            const float sp     = (float)sp2[0] + (float)sp2[1];
            const float t_half = (float)th2[0] + (float)th2[1];

            // one cross-half exchange for (sp, t_half) packed as 2xf16
            U32F pkd, oth;
            pkd.h = pkrtz(sp, t_half);
            oth.u = (unsigned int)__shfl_xor((int)pkd.u, 32, 64);
            const float sc = sp + (float)oth.h[0];
            const float tf = t_half + (float)oth.h[1];

            // no-max accumulate (scores O(0.03) << 88; h dups cancel in ST/S)
            const float ex = (q < NPAIRS) ? __expf(sc) : 0.f;
            s_run  += ex;
            st_run += ex * tf;
        }

        // wave butterfly, stash into this element's reduce slots
        #pragma unroll
        for (int m = 1; m < 64; m <<= 1) {
            s_run  += __shfl_xor(s_run, m, 64);
            st_run += __shfl_xor(st_run, m, 64);
        }
        if (lane == 0) { red_s[grp][e & 1][wg] = s_run; red_st[grp][e & 1][wg] = st_run; }

        // write next element's gather into the other LDS buffer
        if (e + 1 < NSEQ) GWRITE((e + 1) & 1);
        __syncthreads();

        if (tg == 0) {   // one thread per group
            const float S  = red_s[grp][e & 1][0] + red_s[grp][e & 1][1]
                           + red_s[grp][e & 1][2] + red_s[grp][e & 1][3];
            const float ST = red_st[grp][e & 1][0] + red_st[grp][e & 1][1]
                           + red_st[grp][e & 1][2] + red_st[grp][e & 1][3];
            out[b0 + ei] = ST / S + csum_s[ei];
        }
    }

#undef GISSUE
#undef GWRITE
}

extern "C" void kernel_launch(void* const* d_in, const int* in_sizes, int n_in,
                              void* d_out, int out_size, void* d_ws, size_t ws_size,
                              hipStream_t stream) {
    const int*   features    = (const int*)d_in[0];
    const float* emb_table   = (const float*)d_in[1];
    const float* coeff_table = (const float*)d_in[2];
    const float* bias        = (const float*)d_in[3];
    const float* att_w       = (const float*)d_in[4];
    const float* att_b       = (const float*)d_in[5];
    const float* pvec        = (const float*)d_in[6];
    const float* wvec        = (const float*)d_in[7];
    float* out = (float*)d_out;

    const int batch = in_sizes[0] / NFIELDS;   // 2048
    afm_kernel<<<batch / (NGRP * NSEQ), NTHREADS, 0, stream>>>(
        features, emb_table, coeff_table, bias, att_w, att_b, pvec, wvec, out);
}